// Round 1
// baseline (386.576 us; speedup 1.0000x reference)
//
#include <hip/hip_runtime.h>
#include <hip/hip_bf16.h>

#define NDIM 512
#define EPS 1e-4f

// ---------- helpers ----------
__device__ inline float blo(uint x) { return __uint_as_float(x << 16); }
__device__ inline float bhi(uint x) { return __uint_as_float(x & 0xFFFF0000u); }
__device__ inline unsigned short f2bf(float f) {
    uint u = __float_as_uint(f);
    uint r = u + 0x7FFFu + ((u >> 16) & 1u);  // round-to-nearest-even
    return (unsigned short)(r >> 16);
}

// ---------- K0: fp32 -> bf16 (A + eps), only rows r < n ----------
__global__ void k_convert(const float* __restrict__ A, const int* __restrict__ nrows,
                          unsigned short* __restrict__ Abf) {
    int b = blockIdx.y;
    int n = nrows[b];
    int idx = (blockIdx.x * 256 + threadIdx.x) << 2;   // 4 elements/thread
    int r = idx >> 9;
    if (r >= n) return;
    size_t off = (size_t)b * (NDIM * NDIM) + idx;
    float4 a = *(const float4*)(A + off);
    ushort4 o;
    o.x = f2bf(a.x + EPS);
    o.y = f2bf(a.y + EPS);
    o.z = f2bf(a.z + EPS);
    o.w = f2bf(a.w + EPS);
    *(ushort4*)(Abf + off) = o;
}

// ---------- col step: v[c] = 1 / sum_{r<n} Abf[r,c]*u[r]  (u==null -> u=1) ----------
// grid (4, B); block 256 = 4 waves; tile = 128 columns; lane owns 2 adjacent cols.
__global__ __launch_bounds__(256) void k_col(const unsigned short* __restrict__ Abf,
                                             const float* __restrict__ u,
                                             const int* __restrict__ nrows,
                                             float* __restrict__ v) {
    int b = blockIdx.y;
    int n = nrows[b];
    int base_c = blockIdx.x << 7;
    int t = threadIdx.x;
    if (base_c >= n) {                 // whole tile outside block: v = 0
        if (t < 128) v[(b << 9) + base_c + t] = 0.f;
        return;
    }
    __shared__ float su[NDIM];
    __shared__ float2 red[4][64];
    if (u) { su[t] = u[(b << 9) + t]; su[t + 256] = u[(b << 9) + t + 256]; }
    else   { su[t] = 1.f;             su[t + 256] = 1.f; }
    __syncthreads();
    int wave = t >> 6, lane = t & 63;
    int c0 = base_c + (lane << 1);
    float a0 = 0.f, a1 = 0.f;
    if (c0 < n) {
        const unsigned short* p = Abf + (size_t)b * (NDIM * NDIM) + c0;
        int r = wave;
        for (; r + 12 < n; r += 16) {          // 4 loads in flight
            uint x0 = *(const uint*)(p + (size_t)(r) * NDIM);
            uint x1 = *(const uint*)(p + (size_t)(r + 4) * NDIM);
            uint x2 = *(const uint*)(p + (size_t)(r + 8) * NDIM);
            uint x3 = *(const uint*)(p + (size_t)(r + 12) * NDIM);
            float u0 = su[r], u1 = su[r + 4], u2 = su[r + 8], u3 = su[r + 12];
            a0 += u0 * blo(x0) + u1 * blo(x1) + u2 * blo(x2) + u3 * blo(x3);
            a1 += u0 * bhi(x0) + u1 * bhi(x1) + u2 * bhi(x2) + u3 * bhi(x3);
        }
        for (; r < n; r += 4) {
            uint x = *(const uint*)(p + (size_t)r * NDIM);
            float uu = su[r];
            a0 += uu * blo(x);
            a1 += uu * bhi(x);
        }
    }
    red[wave][lane] = make_float2(a0, a1);
    __syncthreads();
    if (t < 128) {
        int lq = t >> 1, comp = t & 1;
        float s = 0.f;
#pragma unroll
        for (int w = 0; w < 4; ++w) {
            float2 pp = red[w][lq];
            s += comp ? pp.y : pp.x;
        }
        int c = base_c + t;
        v[(b << 9) + c] = (c < n) ? (1.0f / s) : 0.f;
    }
}

// ---------- row step: u[r] = 1 / sum_{c<n} Abf[r,c]*v[c] ----------
// grid (128, B); block 256 = 4 waves; wave handles one row. v[c]=0 for c>=n masks cols.
__global__ __launch_bounds__(256) void k_row(const unsigned short* __restrict__ Abf,
                                             const float* __restrict__ v,
                                             const int* __restrict__ nrows,
                                             float* __restrict__ u) {
    int b = blockIdx.y;
    int n = nrows[b];
    int r0 = blockIdx.x << 2;
    int t = threadIdx.x;
    if (r0 >= n) {                     // all 4 rows outside block
        if (t < 4) u[(b << 9) + r0 + t] = 0.f;
        return;
    }
    __shared__ float sv[NDIM];
    sv[t] = v[(b << 9) + t];
    sv[t + 256] = v[(b << 9) + t + 256];
    __syncthreads();
    int wave = t >> 6, lane = t & 63;
    int r = r0 + wave;
    if (r >= n) {
        if (lane == 0) u[(b << 9) + r] = 0.f;
        return;
    }
    const uint2* row = (const uint2*)(Abf + (size_t)b * (NDIM * NDIM) + (size_t)r * NDIM);
    float acc = 0.f;
    int jmax = (n + 255) >> 8;         // 1 or 2 chunks of 256 cols
    for (int j = 0; j < jmax; ++j) {
        uint2 x = row[(j << 6) + lane];
        float4 vv = *(const float4*)&sv[(j << 8) + (lane << 2)];
        acc += blo(x.x) * vv.x + bhi(x.x) * vv.y + blo(x.y) * vv.z + bhi(x.y) * vv.w;
    }
#pragma unroll
    for (int o = 32; o; o >>= 1) acc += __shfl_xor(acc, o, 64);
    if (lane == 0) u[(b << 9) + r] = 1.0f / acc;
}

// ---------- final: out = (A+eps)*u[r]*v[c] inside block, 0 outside ----------
__global__ void k_final(const float* __restrict__ A, const float* __restrict__ u,
                        const float* __restrict__ v, const int* __restrict__ nrows,
                        float* __restrict__ out) {
    int b = blockIdx.y;
    int n = nrows[b];
    int idx = (blockIdx.x * 256 + threadIdx.x) << 2;
    int r = idx >> 9, c = idx & 511;
    size_t off = (size_t)b * (NDIM * NDIM) + idx;
    if (r >= n) {
        *(float4*)(out + off) = make_float4(0.f, 0.f, 0.f, 0.f);
        return;
    }
    float4 a = *(const float4*)(A + off);
    float ur = u[(b << 9) + r];
    float4 vv = *(const float4*)(v + (b << 9) + c);   // v==0 for c>=n handles col mask
    float4 o;
    o.x = (a.x + EPS) * ur * vv.x;
    o.y = (a.y + EPS) * ur * vv.y;
    o.z = (a.z + EPS) * ur * vv.z;
    o.w = (a.w + EPS) * ur * vv.w;
    *(float4*)(out + off) = o;
}

extern "C" void kernel_launch(void* const* d_in, const int* in_sizes, int n_in,
                              void* d_out, int out_size, void* d_ws, size_t ws_size,
                              hipStream_t stream) {
    const float* A = (const float*)d_in[0];
    const int* nrows = (const int*)d_in[1];
    float* out = (float*)d_out;
    const int B = in_sizes[1];                 // 128

    float* u = (float*)d_ws;
    float* v = u + (size_t)B * NDIM;
    size_t uv_bytes = (size_t)2 * B * NDIM * sizeof(float);
    size_t abf_bytes = (size_t)B * NDIM * NDIM * sizeof(unsigned short);
    unsigned short* Abf;
    if (ws_size >= uv_bytes + abf_bytes)
        Abf = (unsigned short*)((char*)d_ws + uv_bytes);
    else
        Abf = (unsigned short*)d_out;          // dead before k_final writes out

    k_convert<<<dim3(NDIM * NDIM / 1024, B), 256, 0, stream>>>(A, nrows, Abf);

    const float* uin = nullptr;
    for (int it = 0; it < 10; ++it) {
        if ((it & 1) == 0) {
            k_col<<<dim3(4, B), 256, 0, stream>>>(Abf, uin, nrows, v);
        } else {
            k_row<<<dim3(NDIM / 4, B), 256, 0, stream>>>(Abf, v, nrows, u);
            uin = u;
        }
    }
    k_final<<<dim3(NDIM * NDIM / 1024, B), 256, 0, stream>>>(A, u, v, nrows, out);
}